// Round 4
// baseline (3047.764 us; speedup 1.0000x reference)
//
#include <hip/hip_runtime.h>
#include <hip/hip_bf16.h>
#include <stdint.h>

// MultiHeadSelfAttention (Swin window attn): B=2048 windows, C=512, N=49, h=8, d=64.
// Round 4: attack latency-bound 1-block/CU (round 3: 785us, Occ 24%, all pipes idle).
//   K0 prep: weights->f16, bias[8][64][64] f32 (pad masked -1e9).
//   K1 transpose: x [b][512][49] f32 -> xT [b][64tok][512ch] f16, XOR-swizzled rows,
//      pad tokens zeroed. LDS-staged, coalesced both sides.
//   K2 fused (512 thr, 8 waves, wave-per-head, LDS = 8x8KB tiles ONLY = 64KB ->
//      2 blocks/CU, 16 waves/CU): per wave: Q,K,V GEMMs with A-frags straight from
//      global xT (L2-resident), S=QK^T, reg softmax, PV, O->own tile, 1 barrier,
//      fused out-proj with f32x4 stores.
// ws: Wqkv f16 | Wproj f16 | bias f32 | xT f16 (128MB). ~130.4MB total.

#define BATCH 2048
#define CIN 512
#define NTOK 49
#define NHEAD 8

typedef __attribute__((ext_vector_type(4))) float    ffrag;
typedef __attribute__((ext_vector_type(8))) _Float16 hfrag;
typedef __attribute__((ext_vector_type(4))) float    f32x4;
typedef __attribute__((ext_vector_type(4), aligned(4))) float f32x4u; // 4B-aligned vec store

#define WQKV_BYTES  (1536*512*2)
#define WPROJ_OFF   ((size_t)WQKV_BYTES)
#define WPROJ_BYTES (512*512*2)
#define BIAS_OFF    (WPROJ_OFF + WPROJ_BYTES)
#define BIAS_BYTES  (8*64*64*4)
#define XT_OFF      (BIAS_OFF + BIAS_BYTES)     // 2228224, 16B aligned
// xT: 2048 windows * 64 rows * 512 ch * 2B = 128MB

// ---------------------------------------------------------------- prep ------
__global__ void prep_kernel(const float* __restrict__ qkv_w,
                            const float* __restrict__ proj_w,
                            const float* __restrict__ bias_table,
                            const int*   __restrict__ rel_index,
                            _Float16* __restrict__ wqkv,
                            _Float16* __restrict__ wproj,
                            float*    __restrict__ biasf) {
    int idx = blockIdx.x * blockDim.x + threadIdx.x;
    const int NQ = 1536*512;
    const int NP = 512*512;
    if (idx < NQ) {
        wqkv[idx] = (_Float16)qkv_w[idx];
    } else if (idx < NQ + NP) {
        int i = idx - NQ;
        wproj[i] = (_Float16)proj_w[i];
    } else if (idx < NQ + NP + 8*64*64) {
        int i = idx - NQ - NP;
        int h = i >> 12;
        int n = (i >> 6) & 63;
        int m = i & 63;
        float v;
        if (m >= NTOK)      v = -1e9f;   // masked key columns (pad)
        else if (n >= NTOK) v = 0.0f;    // pad query rows: finite, discarded later
        else                v = bias_table[rel_index[n*NTOK + m]*NHEAD + h];
        biasf[i] = v;
    }
}

// ----------------------------------------------------------- transpose ------
// x[b] [512][49] f32 -> xT[b] [64tok][512ch] f16, row byte = tok*1024,
// within-row byte = (2c) ^ ((tok&7)<<4). Pad rows 49-63 zeroed.
__global__ __launch_bounds__(256) void transpose_kernel(
        const float* __restrict__ x, _Float16* __restrict__ xT) {
    __shared__ char lbuf[65536];
    const int b   = blockIdx.x;
    const int tid = threadIdx.x;

    const f32x4* xb = (const f32x4*)(x + (size_t)b * (CIN*NTOK));
    #pragma unroll
    for (int it = 0; it < 25; ++it) {
        int f4 = tid + it*256;
        if (f4 < 6272) {                       // 25088 floats / 4
            f32x4 v = xb[f4];
            int base = f4 * 4;
            #pragma unroll
            for (int e = 0; e < 4; ++e) {
                int idx = base + e;
                int c = idx / NTOK;
                int n = idx - c*NTOK;
                *(_Float16*)(lbuf + n*1024 + ((c*2) ^ ((n&7)<<4))) = (_Float16)v[e];
            }
        }
    }
    // zero pad token rows 49..63 (bytes [50176, 65536))
    for (int i = tid; i < 3840; i += 256)
        *(uint32_t*)(lbuf + 50176 + i*4) = 0u;
    __syncthreads();

    // coalesced 16B copy LDS -> global (layout identical)
    const f32x4* src = (const f32x4*)lbuf;
    f32x4*       dst = (f32x4*)(xT + (size_t)b * 32768);
    #pragma unroll
    for (int it = 0; it < 16; ++it)
        dst[tid + it*256] = src[tid + it*256];
}

// -------------------------------------------------------- fused everything --
// LDS 64KB: 8 per-wave 8KB tiles (Q -> K -> P -> V^T -> O sequentially).
// Tile swizzle: byte_in_row ^= (row&7)<<4, rows 128B.
__global__ __launch_bounds__(512, 4) void mhsa_fused_kernel(
        const _Float16* __restrict__ xT,
        const _Float16* __restrict__ wqkv,
        const _Float16* __restrict__ wproj,
        const float* __restrict__ projb,
        const float* __restrict__ biasf,
        float* __restrict__ out) {
    extern __shared__ char lds[];

    const int b    = blockIdx.x;
    const int tid  = threadIdx.x;
    const int wid  = tid >> 6;                    // wave id == head id
    const int lane = tid & 63;
    const int l15  = lane & 15;
    const int g    = lane >> 4;
    char* tile = lds + (wid << 13);               // per-wave 8KB
    const char* xw = (const char*)(xT + (size_t)b * 32768);

    const int h = wid;
    hfrag qa[8], kb[8], pa[8], vb[8];   // [mt*2+ksp], all indices compile-time

    // read 8 A/B fragments (rows 16*mt + l15, k-halves ksp) from per-wave tile
    auto read_frags = [&](hfrag* dst) {
        #pragma unroll
        for (int mt = 0; mt < 4; ++mt)
            #pragma unroll
            for (int ksp = 0; ksp < 2; ++ksp)
                dst[mt*2+ksp] = *(const hfrag*)(tile + (16*mt + l15)*128 +
                                  ((ksp*64 + g*16) ^ ((l15&7)<<4)));
    };

    // one QKV pass: 64 output channels (s,h), M=64 tok, K=512. acc 64 VGPR.
    // A-frags straight from global xT (window-resident in L2).
    auto qkv_pass = [&](int s, int trans) {
        ffrag acc[4][4];
        #pragma unroll
        for (int nt = 0; nt < 4; ++nt)
            #pragma unroll
            for (int mt = 0; mt < 4; ++mt) { ffrag z = {0.f,0.f,0.f,0.f}; acc[nt][mt] = z; }

        const _Float16* wb = wqkv + ((size_t)(s*512 + h*64 + l15))*512 + g*8;
        hfrag Bf[2][4];
        #pragma unroll
        for (int nt = 0; nt < 4; ++nt)
            Bf[0][nt] = *(const hfrag*)(wb + nt*8192);

        #pragma unroll
        for (int ks = 0; ks < 16; ++ks) {
            if (ks < 15) {
                #pragma unroll
                for (int nt = 0; nt < 4; ++nt)
                    Bf[(ks+1)&1][nt] = *(const hfrag*)(wb + nt*8192 + (ks+1)*32);
            }
            hfrag Af[4];
            #pragma unroll
            for (int mt = 0; mt < 4; ++mt)
                Af[mt] = *(const hfrag*)(xw + (16*mt + l15)*1024 +
                           ((ks*64 + g*16) ^ ((l15&7)<<4)));
            #pragma unroll
            for (int nt = 0; nt < 4; ++nt)
                #pragma unroll
                for (int mt = 0; mt < 4; ++mt)
                    acc[nt][mt] = __builtin_amdgcn_mfma_f32_16x16x32_f16(
                        Af[mt], Bf[ks&1][nt], acc[nt][mt], 0, 0, 0);
        }
        // epilogue -> tile.  C/D layout: col=l15(outch), rows=4g+i (token).
        #pragma unroll
        for (int nt = 0; nt < 4; ++nt)
            #pragma unroll
            for (int mt = 0; mt < 4; ++mt)
                #pragma unroll
                for (int i = 0; i < 4; ++i) {
                    int tok = 16*mt + 4*g + i;
                    int d   = 16*nt + l15;
                    _Float16 v = (_Float16)acc[nt][mt][i];
                    if (!trans)   // [tok][d]
                        *(_Float16*)(tile + tok*128 + ((2*d) ^ ((tok&7)<<4))) = v;
                    else          // [d][tok]  (V^T for PV B-operand)
                        *(_Float16*)(tile + d*128 + ((2*tok) ^ ((d&7)<<4))) = v;
                }
    };

    // ---- per-wave attention (no cross-wave interaction until proj) ---------
    qkv_pass(0, 0);  read_frags(qa);      // Q [tok][d] -> A-frags
    qkv_pass(1, 0);  read_frags(kb);      // K [tok][d] -> B-frags (l15 = ktok)

    // S = Q K^T  [qtok][ktok]
    ffrag sacc[4][4];                      // [nt=ktok tile][mt=qtok tile]
    #pragma unroll
    for (int nt = 0; nt < 4; ++nt)
        #pragma unroll
        for (int mt = 0; mt < 4; ++mt) { ffrag z = {0.f,0.f,0.f,0.f}; sacc[nt][mt] = z; }
    #pragma unroll
    for (int nt = 0; nt < 4; ++nt)
        #pragma unroll
        for (int mt = 0; mt < 4; ++mt)
            #pragma unroll
            for (int ksp = 0; ksp < 2; ++ksp)
                sacc[nt][mt] = __builtin_amdgcn_mfma_f32_16x16x32_f16(
                    qa[mt*2+ksp], kb[nt*2+ksp], sacc[nt][mt], 0, 0, 0);

    // scale + relative-position bias (pad mask baked into biasf)
    const float* bh = biasf + (h << 12);
    #pragma unroll
    for (int nt = 0; nt < 4; ++nt)
        #pragma unroll
        for (int mt = 0; mt < 4; ++mt)
            #pragma unroll
            for (int i = 0; i < 4; ++i) {
                int n = 16*mt + 4*g + i, m = 16*nt + l15;
                sacc[nt][mt][i] = sacc[nt][mt][i]*0.125f + bh[(n<<6) + m];
            }

    // wave-parallel softmax over ktok (in-lane across nt, 16-lane shfl across l15)
    float rmax[4][4], rsum[4][4];
    #pragma unroll
    for (int mt = 0; mt < 4; ++mt)
        #pragma unroll
        for (int i = 0; i < 4; ++i)
            rmax[mt][i] = fmaxf(fmaxf(sacc[0][mt][i], sacc[1][mt][i]),
                                fmaxf(sacc[2][mt][i], sacc[3][mt][i]));
    #pragma unroll
    for (int off = 1; off <= 8; off <<= 1)
        #pragma unroll
        for (int mt = 0; mt < 4; ++mt)
            #pragma unroll
            for (int i = 0; i < 4; ++i)
                rmax[mt][i] = fmaxf(rmax[mt][i], __shfl_xor(rmax[mt][i], off));
    #pragma unroll
    for (int mt = 0; mt < 4; ++mt)
        #pragma unroll
        for (int i = 0; i < 4; ++i) rsum[mt][i] = 0.0f;
    #pragma unroll
    for (int nt = 0; nt < 4; ++nt)
        #pragma unroll
        for (int mt = 0; mt < 4; ++mt)
            #pragma unroll
            for (int i = 0; i < 4; ++i) {
                float p = __expf(sacc[nt][mt][i] - rmax[mt][i]);
                sacc[nt][mt][i] = p;
                rsum[mt][i] += p;
            }
    #pragma unroll
    for (int off = 1; off <= 8; off <<= 1)
        #pragma unroll
        for (int mt = 0; mt < 4; ++mt)
            #pragma unroll
            for (int i = 0; i < 4; ++i)
                rsum[mt][i] += __shfl_xor(rsum[mt][i], off);

    // write unnormalized P (f16) over tile (K-frags already consumed)
    #pragma unroll
    for (int nt = 0; nt < 4; ++nt)
        #pragma unroll
        for (int mt = 0; mt < 4; ++mt)
            #pragma unroll
            for (int i = 0; i < 4; ++i) {
                int n = 16*mt + 4*g + i, m = 16*nt + l15;
                *(_Float16*)(tile + n*128 + ((2*m) ^ ((n&7)<<4))) = (_Float16)sacc[nt][mt][i];
            }
    read_frags(pa);                       // P [qtok][ktok] -> A-frags

    float inv[4][4];
    #pragma unroll
    for (int mt = 0; mt < 4; ++mt)
        #pragma unroll
        for (int i = 0; i < 4; ++i) inv[mt][i] = 1.0f / rsum[mt][i];

    qkv_pass(2, 1);  read_frags(vb);      // V^T [d][tok] -> B-frags (l15 = d)

    // O = P V   [qtok][d]
    ffrag oacc[4][4];                     // [dt][mt]
    #pragma unroll
    for (int dt = 0; dt < 4; ++dt)
        #pragma unroll
        for (int mt = 0; mt < 4; ++mt) { ffrag z = {0.f,0.f,0.f,0.f}; oacc[dt][mt] = z; }
    #pragma unroll
    for (int dt = 0; dt < 4; ++dt)
        #pragma unroll
        for (int mt = 0; mt < 4; ++mt)
            #pragma unroll
            for (int ksp = 0; ksp < 2; ++ksp)
                oacc[dt][mt] = __builtin_amdgcn_mfma_f32_16x16x32_f16(
                    pa[mt*2+ksp], vb[dt*2+ksp], oacc[dt][mt], 0, 0, 0);

    // O (normalized) -> own tile as [tok][d] (own-wave DS order, no barrier)
    #pragma unroll
    for (int dt = 0; dt < 4; ++dt)
        #pragma unroll
        for (int mt = 0; mt < 4; ++mt)
            #pragma unroll
            for (int i = 0; i < 4; ++i) {
                int tok = 16*mt + 4*g + i;
                int d   = 16*dt + l15;
                float v = oacc[dt][mt][i] * inv[mt][i];
                *(_Float16*)(tile + tok*128 + ((2*d) ^ ((tok&7)<<4))) = (_Float16)v;
            }
    __syncthreads();   // the ONE barrier: all 8 O-tiles ready

    // ---- out-proj: D[tok][o] = O[tok][0..511] . Wproj[o][:] ----------------
    {
        ffrag acc[4][4];                  // [nt=outch tile][mt=tok tile]
        #pragma unroll
        for (int nt = 0; nt < 4; ++nt)
            #pragma unroll
            for (int mt = 0; mt < 4; ++mt) { ffrag z = {0.f,0.f,0.f,0.f}; acc[nt][mt] = z; }

        const _Float16* wb = wproj + ((size_t)((wid<<6) + l15))*512 + g*8;
        hfrag Bf[2][4];
        #pragma unroll
        for (int nt = 0; nt < 4; ++nt)
            Bf[0][nt] = *(const hfrag*)(wb + nt*8192);

        #pragma unroll
        for (int ks = 0; ks < 16; ++ks) {
            if (ks < 15) {
                #pragma unroll
                for (int nt = 0; nt < 4; ++nt)
                    Bf[(ks+1)&1][nt] = *(const hfrag*)(wb + nt*8192 + (ks+1)*32);
            }
            // A-frags across the 8 head tiles: channel c0 = ks*32 + g*8
            hfrag Af[4];
            {
                const int c0 = ks*32 + g*8;
                const char* tb = lds + ((c0 >> 6) << 13);
                const int doff = 2*(c0 & 63);
                #pragma unroll
                for (int mt = 0; mt < 4; ++mt)
                    Af[mt] = *(const hfrag*)(tb + (16*mt + l15)*128 +
                               (doff ^ ((l15&7)<<4)));
            }
            #pragma unroll
            for (int nt = 0; nt < 4; ++nt)
                #pragma unroll
                for (int mt = 0; mt < 4; ++mt)
                    acc[nt][mt] = __builtin_amdgcn_mfma_f32_16x16x32_f16(
                        Af[mt], Bf[ks&1][nt], acc[nt][mt], 0, 0, 0);
        }

        #pragma unroll
        for (int nt = 0; nt < 4; ++nt) {
            int o = (wid<<6) + 16*nt + l15;
            float pb = projb[o];
            float* op = out + ((size_t)b*512 + o)*NTOK;
            #pragma unroll
            for (int mt = 0; mt < 3; ++mt) {        // n = 0..47: full f32x4
                f32x4u v4;
                #pragma unroll
                for (int i = 0; i < 4; ++i) v4[i] = acc[nt][mt][i] + pb;
                *(f32x4u*)(op + 16*mt + 4*g) = v4;
            }
            if (g == 0)                              // n = 48 (real token tail)
                op[48] = acc[nt][3][0] + pb;
        }
    }
}

// ---------------------------------------------------------------------------
extern "C" void kernel_launch(void* const* d_in, const int* in_sizes, int n_in,
                              void* d_out, int out_size, void* d_ws, size_t ws_size,
                              hipStream_t stream) {
    const float* x      = (const float*)d_in[0];
    const float* qkv_w  = (const float*)d_in[1];
    const float* proj_w = (const float*)d_in[2];
    const float* proj_b = (const float*)d_in[3];
    const float* bias_t = (const float*)d_in[4];
    const int*   rel    = (const int*)d_in[5];
    float* out = (float*)d_out;

    char* ws = (char*)d_ws;
    _Float16* wqkv  = (_Float16*)(ws);
    _Float16* wproj = (_Float16*)(ws + WPROJ_OFF);
    float*    biasf = (float*)(ws + BIAS_OFF);
    _Float16* xT    = (_Float16*)(ws + XT_OFF);
    // requires ws_size >= ~130.4 MB (2228224 + 2048*64*512*2)

    (void)hipFuncSetAttribute((const void*)mhsa_fused_kernel,
                              hipFuncAttributeMaxDynamicSharedMemorySize,
                              65536);

    const int prep_total = 1536*512 + 512*512 + 8*64*64;
    prep_kernel<<<(prep_total + 255)/256, 256, 0, stream>>>(
        qkv_w, proj_w, bias_t, rel, wqkv, wproj, biasf);
    transpose_kernel<<<BATCH, 256, 0, stream>>>(x, xT);
    mhsa_fused_kernel<<<BATCH, 512, 65536, stream>>>(
        xT, wqkv, wproj, proj_b, biasf, out);
}

// Round 5
// 1042.347 us; speedup vs baseline: 2.9239x; 2.9239x over previous
//
#include <hip/hip_runtime.h>
#include <stdint.h>

// MultiHeadSelfAttention (Swin window attn): B=2048, C=512, N=49, h=8, d=64.
// Round 5: fix round-4's spill (VGPR budget 128, peak live was ~150 -> 8.9GB
// scratch traffic) and uncoalesced fragment gathers (1KB-stride 16B/lane).
//   - All MFMA fragments pre-packed fragment-major in ws: one coalesced
//     dwordx4 per lane per fragment (wqkvP, wprojP, biasP, xTP).
//   - Register-lean wave schedule (peak live ~105 <= 128):
//     Q full-pass(acc64)->tile->qa regs; K,V as 2 half-passes(acc32) with
//     qa/pa held; kb/vb read on-the-fly from LDS; P normalized pre-store
//     (inv dies early); V^T epilogue = packed b64 writes.
//   - 8 waves wave-per-head, LDS 64KB (8x8KB tiles), 1 barrier, fused proj.
// ws: wqkvP 1.5MB | wprojP 0.5MB | biasP 128KB | xTP 128MB  (~130.4MB).

#define BATCH 2048
#define CIN 512
#define NTOK 49
#define NHEAD 8

typedef __attribute__((ext_vector_type(4))) float    ffrag;
typedef __attribute__((ext_vector_type(8))) _Float16 hfrag;
typedef __attribute__((ext_vector_type(4))) float    f32x4;
typedef __attribute__((ext_vector_type(4), aligned(4))) float f32x4u;
typedef __attribute__((ext_vector_type(4))) _Float16 h4;    // 8B packed store

#define WQKVP_OFF    ((size_t)0)                    // 24*64 frags * 1KB
#define WQKVP_BYTES  (24*64*1024)
#define WPROJP_OFF   (WQKVP_OFF + WQKVP_BYTES)      // 8*64 frags * 1KB
#define WPROJP_BYTES (8*64*1024)
#define BIASP_OFF    (WPROJP_OFF + WPROJP_BYTES)    // 8*4*4*64 chunks * 16B
#define BIASP_BYTES  (8*4*4*64*16)
#define XTP_OFF      (BIASP_OFF + BIASP_BYTES)      // 2228224; + 2048*64KB

// ---------------------------------------------------------------- prep ------
// One thread per 16B fragment chunk. Frag content for (matrix m, nt, ks):
// lane holds W[o = nt*16 + (lane&15)][c = ks*32 + (lane>>4)*8 + 0..7].
__global__ void prep_kernel(const float* __restrict__ qkv_w,
                            const float* __restrict__ proj_w,
                            const float* __restrict__ bias_table,
                            const int*   __restrict__ rel_index,
                            _Float16* __restrict__ wqkvP,
                            _Float16* __restrict__ wprojP,
                            float*    __restrict__ biasP) {
    int q = blockIdx.x * blockDim.x + threadIdx.x;
    if (q < 98304) {                         // wqkvP: 24 matrices (s*8+h)
        int lane = q & 63, fid = q >> 6;
        int ks = fid & 15, nt = (fid >> 4) & 3, m = fid >> 6;
        int h = m & 7, s = m >> 3;
        int o  = s*512 + h*64 + nt*16 + (lane & 15);
        int cb = ks*32 + (lane >> 4)*8;
        const float* src = qkv_w + (size_t)o*512 + cb;
        _Float16* dst = wqkvP + (size_t)q*8;
        #pragma unroll
        for (int e = 0; e < 8; ++e) dst[e] = (_Float16)src[e];
    } else if (q < 131072) {                 // wprojP: 8 matrices (wid)
        int r = q - 98304;
        int lane = r & 63, fid = r >> 6;
        int ks = fid & 15, nt = (fid >> 4) & 3, wd = fid >> 6;
        int o  = wd*64 + nt*16 + (lane & 15);
        int cb = ks*32 + (lane >> 4)*8;
        const float* src = proj_w + (size_t)o*512 + cb;
        _Float16* dst = wprojP + (size_t)r*8;
        #pragma unroll
        for (int e = 0; e < 8; ++e) dst[e] = (_Float16)src[e];
    } else if (q < 139264) {                 // biasP[h][nt][mt][lane] f32x4
        int r = q - 131072;
        int lane = r & 63, idx = r >> 6;
        int mt = idx & 3, nt = (idx >> 2) & 3, hh = idx >> 4;
        int m  = 16*nt + (lane & 15);
        int nb = 16*mt + (lane >> 4)*4;
        f32x4 v;
        #pragma unroll
        for (int i = 0; i < 4; ++i) {
            int n = nb + i;
            float val;
            if (m >= NTOK)      val = -1e9f;   // masked key cols (pad)
            else if (n >= NTOK) val = 0.0f;    // pad query rows, discarded
            else                val = bias_table[rel_index[n*NTOK + m]*NHEAD + hh];
            v[i] = val;
        }
        *(f32x4*)(biasP + (size_t)r*4) = v;
    }
}

// ---------------------------------------------------------------- packx -----
// x[b][512][49] f32 -> xTP[b]: 64 A-frags (mt*16+ks), frag-major, pad tok = 0.
// Writes fully coalesced (thread q -> 16B at q*16); reads 64B-coalesced per
// 16-lane group (consecutive tok).
__global__ __launch_bounds__(256) void packx_kernel(
        const float* __restrict__ x, _Float16* __restrict__ xTP) {
    const int b = blockIdx.x, tid = threadIdx.x;
    const float* xb = x + (size_t)b * (CIN*NTOK);
    _Float16* dst = xTP + (size_t)b * 32768;
    #pragma unroll
    for (int it = 0; it < 16; ++it) {
        int q = it*256 + tid;
        int lane = q & 63, fid = q >> 6;
        int mt = fid >> 4, ks = fid & 15;
        int tok = mt*16 + (lane & 15);
        int cb  = ks*32 + (lane >> 4)*8;
        hfrag v;
        if (tok < NTOK) {
            #pragma unroll
            for (int e = 0; e < 8; ++e) v[e] = (_Float16)xb[(cb + e)*NTOK + tok];
        } else {
            #pragma unroll
            for (int e = 0; e < 8; ++e) v[e] = (_Float16)0.0f;
        }
        *(hfrag*)(dst + (size_t)q*8) = v;
    }
}

// -------------------------------------------------------- fused everything --
// LDS 64KB: 8 per-wave 8KB tiles (Q -> K -> P -> V^T -> O sequentially).
// Tile swizzle: byte_in_row ^= (row&7)<<4, rows 128B.
__global__ __launch_bounds__(512, 4) void mhsa_fused_kernel(
        const _Float16* __restrict__ xTP,
        const _Float16* __restrict__ wqkvP,
        const _Float16* __restrict__ wprojP,
        const float* __restrict__ projb,
        const float* __restrict__ biasP,
        float* __restrict__ out) {
    extern __shared__ char lds[];
    const int b    = blockIdx.x;
    const int tid  = threadIdx.x;
    const int wid  = tid >> 6;                 // wave id == head id
    const int lane = tid & 63;
    const int l15  = lane & 15;
    const int g    = lane >> 4;
    char* tile = lds + (wid << 13);            // per-wave 8KB
    const _Float16* xw = xTP + (size_t)b * 32768;
    const int h = wid;

    // ---- Q: full pass (acc[4][4]) -> tile [tok][d] -------------------------
    {
        ffrag acc[4][4];
        #pragma unroll
        for (int nt = 0; nt < 4; ++nt)
            #pragma unroll
            for (int mt = 0; mt < 4; ++mt) { ffrag z = {0.f,0.f,0.f,0.f}; acc[nt][mt] = z; }
        const _Float16* wb = wqkvP + ((size_t)h << 15);        // m = h (s=0)
        #pragma unroll
        for (int ks = 0; ks < 16; ++ks) {
            hfrag Bf[4], Af[4];
            #pragma unroll
            for (int nt = 0; nt < 4; ++nt)
                Bf[nt] = *(const hfrag*)(wb + ((nt*16 + ks) << 9) + lane*8);
            #pragma unroll
            for (int mt = 0; mt < 4; ++mt)
                Af[mt] = *(const hfrag*)(xw + ((mt*16 + ks) << 9) + lane*8);
            #pragma unroll
            for (int nt = 0; nt < 4; ++nt)
                #pragma unroll
                for (int mt = 0; mt < 4; ++mt)
                    acc[nt][mt] = __builtin_amdgcn_mfma_f32_16x16x32_f16(
                        Af[mt], Bf[nt], acc[nt][mt], 0, 0, 0);
        }
        #pragma unroll
        for (int nt = 0; nt < 4; ++nt)
            #pragma unroll
            for (int mt = 0; mt < 4; ++mt)
                #pragma unroll
                for (int i = 0; i < 4; ++i) {
                    int tok = 16*mt + 4*g + i, d = 16*nt + l15;
                    *(_Float16*)(tile + tok*128 + ((2*d) ^ ((tok&7)<<4))) =
                        (_Float16)acc[nt][mt][i];
                }
    }

    // qa: Q A-frags (rows 16*mt+l15, k-halves ksp) — 32 VGPR, live thru S
    hfrag qa[8];
    #pragma unroll
    for (int mt = 0; mt < 4; ++mt)
        #pragma unroll
        for (int ksp = 0; ksp < 2; ++ksp)
            qa[mt*2+ksp] = *(const hfrag*)(tile + (16*mt + l15)*128 +
                              ((ksp*64 + g*16) ^ ((l15&7)<<4)));

    // ---- K: two half-passes (acc[2][4], qa stays live) -> tile [tok][d] ----
    #pragma unroll
    for (int nh = 0; nh < 2; ++nh) {
        ffrag acc[2][4];
        #pragma unroll
        for (int j = 0; j < 2; ++j)
            #pragma unroll
            for (int mt = 0; mt < 4; ++mt) { ffrag z = {0.f,0.f,0.f,0.f}; acc[j][mt] = z; }
        const _Float16* wb = wqkvP + ((size_t)(8 + h) << 15);  // m = 8+h (s=1)
        #pragma unroll
        for (int ks = 0; ks < 16; ++ks) {
            hfrag Bf[2], Af[4];
            #pragma unroll
            for (int j = 0; j < 2; ++j)
                Bf[j] = *(const hfrag*)(wb + (((2*nh + j)*16 + ks) << 9) + lane*8);
            #pragma unroll
            for (int mt = 0; mt < 4; ++mt)
                Af[mt] = *(const hfrag*)(xw + ((mt*16 + ks) << 9) + lane*8);
            #pragma unroll
            for (int j = 0; j < 2; ++j)
                #pragma unroll
                for (int mt = 0; mt < 4; ++mt)
                    acc[j][mt] = __builtin_amdgcn_mfma_f32_16x16x32_f16(
                        Af[mt], Bf[j], acc[j][mt], 0, 0, 0);
        }
        #pragma unroll
        for (int j = 0; j < 2; ++j)
            #pragma unroll
            for (int mt = 0; mt < 4; ++mt)
                #pragma unroll
                for (int i = 0; i < 4; ++i) {
                    int tok = 16*mt + 4*g + i, d = 16*(2*nh + j) + l15;
                    *(_Float16*)(tile + tok*128 + ((2*d) ^ ((tok&7)<<4))) =
                        (_Float16)acc[j][mt][i];
                }
    }

    // ---- S = Q K^T (kb on-the-fly from tile) -------------------------------
    ffrag sacc[4][4];                          // [nt=ktok tile][mt=qtok tile]
    #pragma unroll
    for (int nt = 0; nt < 4; ++nt)
        #pragma unroll
        for (int mt = 0; mt < 4; ++mt) { ffrag z = {0.f,0.f,0.f,0.f}; sacc[nt][mt] = z; }
    #pragma unroll
    for (int ksp = 0; ksp < 2; ++ksp)
        #pragma unroll
        for (int nt = 0; nt < 4; ++nt) {
            hfrag kb = *(const hfrag*)(tile + (16*nt + l15)*128 +
                          ((ksp*64 + g*16) ^ ((l15&7)<<4)));
            #pragma unroll
            for (int mt = 0; mt < 4; ++mt)
                sacc[nt][mt] = __builtin_amdgcn_mfma_f32_16x16x32_f16(
                    qa[mt*2+ksp], kb, sacc[nt][mt], 0, 0, 0);
        }

    // ---- scale + bias (coalesced biasP), wave-parallel softmax -------------
    #pragma unroll
    for (int nt = 0; nt < 4; ++nt)
        #pragma unroll
        for (int mt = 0; mt < 4; ++mt) {
            f32x4 bv = *(const f32x4*)(biasP +
                         ((size_t)(((h*4 + nt)*4 + mt)*64 + lane)) * 4);
            #pragma unroll
            for (int i = 0; i < 4; ++i)
                sacc[nt][mt][i] = sacc[nt][mt][i]*0.125f + bv[i];
        }
    float rmax[4][4], rsum[4][4];
    #pragma unroll
    for (int mt = 0; mt < 4; ++mt)
        #pragma unroll
        for (int i = 0; i < 4; ++i)
            rmax[mt][i] = fmaxf(fmaxf(sacc[0][mt][i], sacc[1][mt][i]),
                                fmaxf(sacc[2][mt][i], sacc[3][mt][i]));
    #pragma unroll
    for (int off = 1; off <= 8; off <<= 1)
        #pragma unroll
        for (int mt = 0; mt < 4; ++mt)
            #pragma unroll
            for (int i = 0; i < 4; ++i)
                rmax[mt][i] = fmaxf(rmax[mt][i], __shfl_xor(rmax[mt][i], off));
    #pragma unroll
    for (int mt = 0; mt < 4; ++mt)
        #pragma unroll
        for (int i = 0; i < 4; ++i) rsum[mt][i] = 0.0f;
    #pragma unroll
    for (int nt = 0; nt < 4; ++nt)
        #pragma unroll
        for (int mt = 0; mt < 4; ++mt)
            #pragma unroll
            for (int i = 0; i < 4; ++i) {
                float p = __expf(sacc[nt][mt][i] - rmax[mt][i]);
                sacc[nt][mt][i] = p;
                rsum[mt][i] += p;
            }
    #pragma unroll
    for (int off = 1; off <= 8; off <<= 1)
        #pragma unroll
        for (int mt = 0; mt < 4; ++mt)
            #pragma unroll
            for (int i = 0; i < 4; ++i)
                rsum[mt][i] += __shfl_xor(rsum[mt][i], off);

    // normalized P -> tile (inv dies here; own-wave DS order protects reads)
    #pragma unroll
    for (int nt = 0; nt < 4; ++nt)
        #pragma unroll
        for (int mt = 0; mt < 4; ++mt)
            #pragma unroll
            for (int i = 0; i < 4; ++i) {
                int n = 16*mt + 4*g + i, m = 16*nt + l15;
                float p = sacc[nt][mt][i] / rsum[mt][i];
                *(_Float16*)(tile + n*128 + ((2*m) ^ ((n&7)<<4))) = (_Float16)p;
            }
    hfrag pa[8];                                // 32 VGPR, live thru PV
    #pragma unroll
    for (int mt = 0; mt < 4; ++mt)
        #pragma unroll
        for (int ksp = 0; ksp < 2; ++ksp)
            pa[mt*2+ksp] = *(const hfrag*)(tile + (16*mt + l15)*128 +
                              ((ksp*64 + g*16) ^ ((l15&7)<<4)));

    // ---- V: two half-passes (pa stays live) -> tile V^T [d][tok], b64 ------
    #pragma unroll
    for (int nh = 0; nh < 2; ++nh) {
        ffrag acc[2][4];
        #pragma unroll
        for (int j = 0; j < 2; ++j)
            #pragma unroll
            for (int mt = 0; mt < 4; ++mt) { ffrag z = {0.f,0.f,0.f,0.f}; acc[j][mt] = z; }
        const _Float16* wb = wqkvP + ((size_t)(16 + h) << 15); // m = 16+h (s=2)
        #pragma unroll
        for (int ks = 0; ks < 16; ++ks) {
            hfrag Bf[2], Af[4];
            #pragma unroll
            for (int j = 0; j < 2; ++j)
                Bf[j] = *(const hfrag*)(wb + (((2*nh + j)*16 + ks) << 9) + lane*8);
            #pragma unroll
            for (int mt = 0; mt < 4; ++mt)
                Af[mt] = *(const hfrag*)(xw + ((mt*16 + ks) << 9) + lane*8);
            #pragma unroll
            for (int j = 0; j < 2; ++j)
                #pragma unroll
                for (int mt = 0; mt < 4; ++mt)
                    acc[j][mt] = __builtin_amdgcn_mfma_f32_16x16x32_f16(
                        Af[mt], Bf[j], acc[j][mt], 0, 0, 0);
        }
        #pragma unroll
        for (int j = 0; j < 2; ++j)
            #pragma unroll
            for (int mt = 0; mt < 4; ++mt) {
                int d = 16*(2*nh + j) + l15;           // V^T row
                h4 pk;
                #pragma unroll
                for (int i = 0; i < 4; ++i) pk[i] = (_Float16)acc[j][mt][i];
                *(h4*)(tile + d*128 + ((32*mt + 8*g) ^ ((d&7)<<4))) = pk;
            }
    }

    // ---- O = P V (vb on-the-fly) -------------------------------------------
    ffrag oacc[4][4];                           // [dt][mt]
    #pragma unroll
    for (int dt = 0; dt < 4; ++dt)
        #pragma unroll
        for (int mt = 0; mt < 4; ++mt) { ffrag z = {0.f,0.f,0.f,0.f}; oacc[dt][mt] = z; }
    #pragma unroll
    for (int ksp = 0; ksp < 2; ++ksp)
        #pragma unroll
        for (int dt = 0; dt < 4; ++dt) {
            hfrag vb = *(const hfrag*)(tile + (16*dt + l15)*128 +
                          ((ksp*64 + g*16) ^ ((l15&7)<<4)));
            #pragma unroll
            for (int mt = 0; mt < 4; ++mt)
                oacc[dt][mt] = __builtin_amdgcn_mfma_f32_16x16x32_f16(
                    pa[mt*2+ksp], vb, oacc[dt][mt], 0, 0, 0);
        }

    // O -> own tile [tok][d] (P already normalized; no inv here)
    #pragma unroll
    for (int dt = 0; dt < 4; ++dt)
        #pragma unroll
        for (int mt = 0; mt < 4; ++mt)
            #pragma unroll
            for (int i = 0; i < 4; ++i) {
                int tok = 16*mt + 4*g + i, d = 16*dt + l15;
                *(_Float16*)(tile + tok*128 + ((2*d) ^ ((tok&7)<<4))) =
                    (_Float16)oacc[dt][mt][i];
            }
    __syncthreads();    // the ONE barrier: all 8 O-tiles ready

    // ---- out-proj: D[tok][o] = O[tok][0..511] . Wproj[o][:] ----------------
    {
        ffrag acc[4][4];
        #pragma unroll
        for (int nt = 0; nt < 4; ++nt)
            #pragma unroll
            for (int mt = 0; mt < 4; ++mt) { ffrag z = {0.f,0.f,0.f,0.f}; acc[nt][mt] = z; }
        const _Float16* wp = wprojP + ((size_t)wid << 15);
        #pragma unroll
        for (int ks = 0; ks < 16; ++ks) {
            hfrag Bf[4], Af[4];
            #pragma unroll
            for (int nt = 0; nt < 4; ++nt)
                Bf[nt] = *(const hfrag*)(wp + ((nt*16 + ks) << 9) + lane*8);
            {   // A-frags span the 8 head tiles: channel c0 = ks*32 + g*8
                const int c0 = ks*32 + g*8;
                const char* tb = lds + ((c0 >> 6) << 13);
                const int doff = 2*(c0 & 63);
                #pragma unroll
                for (int mt = 0; mt < 4; ++mt)
                    Af[mt] = *(const hfrag*)(tb + (16*mt + l15)*128 +
                               (doff ^ ((l15&7)<<4)));
            }
            #pragma unroll
            for (int nt = 0; nt < 4; ++nt)
                #pragma unroll
                for (int mt = 0; mt < 4; ++mt)
                    acc[nt][mt] = __builtin_amdgcn_mfma_f32_16x16x32_f16(
                        Af[mt], Bf[nt], acc[nt][mt], 0, 0, 0);
        }
        #pragma unroll
        for (int nt = 0; nt < 4; ++nt) {
            int o = (wid << 6) + 16*nt + l15;
            float pb = projb[o];
            float* op = out + ((size_t)b*512 + o)*NTOK;
            #pragma unroll
            for (int mt = 0; mt < 3; ++mt) {         // n = 0..47: full f32x4
                f32x4u v4;
                #pragma unroll
                for (int i = 0; i < 4; ++i) v4[i] = acc[nt][mt][i] + pb;
                *(f32x4u*)(op + 16*mt + 4*g) = v4;
            }
            if (g == 0)                              // n = 48 tail
                op[48] = acc[nt][3][0] + pb;
        }
    }
}

// ---------------------------------------------------------------------------
extern "C" void kernel_launch(void* const* d_in, const int* in_sizes, int n_in,
                              void* d_out, int out_size, void* d_ws, size_t ws_size,
                              hipStream_t stream) {
    const float* x      = (const float*)d_in[0];
    const float* qkv_w  = (const float*)d_in[1];
    const float* proj_w = (const float*)d_in[2];
    const float* proj_b = (const float*)d_in[3];
    const float* bias_t = (const float*)d_in[4];
    const int*   rel    = (const int*)d_in[5];
    float* out = (float*)d_out;

    char* ws = (char*)d_ws;
    _Float16* wqkvP  = (_Float16*)(ws + WQKVP_OFF);
    _Float16* wprojP = (_Float16*)(ws + WPROJP_OFF);
    float*    biasP  = (float*)(ws + BIASP_OFF);
    _Float16* xTP    = (_Float16*)(ws + XTP_OFF);
    // requires ws_size >= 2228224 + 2048*65536 = ~130.4 MB

    (void)hipFuncSetAttribute((const void*)mhsa_fused_kernel,
                              hipFuncAttributeMaxDynamicSharedMemorySize,
                              65536);

    prep_kernel<<<544, 256, 0, stream>>>(qkv_w, proj_w, bias_t, rel,
                                         wqkvP, wprojP, biasP);
    packx_kernel<<<BATCH, 256, 0, stream>>>(x, xTP);
    mhsa_fused_kernel<<<BATCH, 512, 65536, stream>>>(
        xTP, wqkvP, wprojP, proj_b, biasP, out);
}